// Round 1
// baseline (153.418 us; speedup 1.0000x reference)
//
#include <hip/hip_runtime.h>

// LFR frame stacking: x (B=64, T=4096, D=80) f32, lens (B,) i32
// out (B, NF=683, M*D=560) f32 ++ new_len (B,) f32
//
// Derived semantics (see analysis): T_all_max = 4099 fixed (lens[0]=T),
// NF = (4099-7)/6+1 = 683. Gather index for output position t=6f+m:
//   src = 0 if t<3; t-3 if t<3+lens[b]; else T-1 (=4095, the reference's
//   where() clamp lands inside the x region, NOT on the tail frame).

constexpr int B    = 64;
constexpr int T    = 4096;
constexpr int D    = 80;
constexpr int NF   = 683;
constexpr int M    = 7;
constexpr int N    = 6;
constexpr int LEFT = 3;

constexpr int D4     = D / 4;        // 20 float4 per frame
constexpr int ROW4   = M * D4;       // 140 float4 per output row
constexpr int TOTAL4 = B * NF * ROW4; // 6,119,680 float4 total

__global__ __launch_bounds__(256) void lfr_kernel(
    const float4* __restrict__ x,     // (B*T*D4) float4
    const int*    __restrict__ lens,  // (B,)
    float4*       __restrict__ out,   // (B*NF*ROW4) float4
    float*        __restrict__ new_len) // (B,)
{
    int idx = blockIdx.x * 256 + threadIdx.x;

    // fused tiny output: new_len
    if (blockIdx.x == 0 && threadIdx.x < B) {
        int L   = lens[threadIdx.x];
        int rem = L % N;
        int rp  = (rem == 1) ? 3 : (rem == 2) ? 2 : (rem == 3) ? 1 : 0;
        new_len[threadIdx.x] = (float)((LEFT + L + rp) / N);
    }

    if (idx >= TOTAL4) return;

    int row = idx / ROW4;          // (b, f) flat
    int r   = idx - row * ROW4;    // position within row, [0,140)
    int b   = row / NF;
    int f   = row - b * NF;
    int m   = r / D4;              // which of M frames
    int d4  = r - m * D4;          // float4 within frame

    int t = f * N + m;             // gather position in padded time axis
    int L = lens[b];

    int src;
    if (t < LEFT)              src = 0;
    else if (t < LEFT + L)     src = t - LEFT;
    else                       src = T - 1;

    out[idx] = x[(b * T + src) * D4 + d4];
}

extern "C" void kernel_launch(void* const* d_in, const int* in_sizes, int n_in,
                              void* d_out, int out_size, void* d_ws, size_t ws_size,
                              hipStream_t stream) {
    const float4* x    = (const float4*)d_in[0];
    const int*    lens = (const int*)d_in[1];
    float*        out  = (float*)d_out;
    float*        nl   = out + (size_t)B * NF * M * D; // new_len after main output

    int blocks = (TOTAL4 + 255) / 256;
    lfr_kernel<<<blocks, 256, 0, stream>>>(x, lens, (float4*)out, nl);
}